// Round 3
// baseline (540.652 us; speedup 1.0000x reference)
//
#include <hip/hip_runtime.h>
#include <math.h>

// OmniRobotPhysics: B=8192 independent trajectories, T=1024 sequential steps.
// R4 -> R5: LDS scheme reverted (R4 regression: single-wave ds_read latency
// cost more than coalescing saved). Two changes:
//  (1) ILP-2: each thread integrates TWO independent trajectories (2p, 2p+1).
//      64 waves, each alone on a SIMD -> the second chain fills the first
//      chain's dependency/memory stall cycles.
//  (2) alignment-aware batched stores: 4 steps (24 floats) buffered in regs,
//      emitted as f2+5xf4+f2 (even rows) or 6xf4 (odd rows; row base byte
//      = b*24600 == 8b mod 16) instead of 12x scattered float2.
// Body-frame recurrence + folded constants kept from R3/R4.

#define MASS_F 2.8f
#define DT_F 0.016f

// F F^T entries (angles {60,130,230,300} deg, R=0.09):
#define M00_F 2.6736481776669306f
#define M11_F 1.3263518223330697f
#define M12_F (-0.025701769743577074f)
#define M22_F 0.0324f

#define PI_F 3.14159265358979323846f
#define TWO_PI_F 6.28318530717958647692f
#define INV_TWO_PI_F 0.15915494309189533577f

#define CHUNK 8   // steps per chunk; 8*3 floats = 6 float4 per trajectory

__device__ __forceinline__ float softplus_f(float x) {
    float ax = fabsf(x);
    return fmaxf(x, 0.0f) + log1pf(expf(-ax));
}

// Full-range sin/cos: used once per trajectory for th0 (and in the tail).
__device__ __forceinline__ void fast_sincos(float th, float* sp, float* cp) {
    const float INV_PIO2 = 0.63661977236758134f;
    const float PIO2_HI  = 1.57079637050628662109375f;
    const float PIO2_LO  = -4.37113900018624283e-8f;
    float kf = rintf(th * INV_PIO2);
    int   k  = (int)kf;
    float r  = fmaf(-kf, PIO2_HI, th);
    r        = fmaf(-kf, PIO2_LO, r);
    float r2 = r * r;
    float ps = fmaf(r2, 2.7183114e-6f, -1.9515296e-4f);
    ps = fmaf(r2, ps, 8.3333310e-3f);
    ps = fmaf(r2, ps, -1.6666667e-1f);
    float sr = fmaf(r * r2, ps, r);
    float pc = fmaf(r2, 2.4760495e-5f, -1.3888889e-3f);
    pc = fmaf(r2, pc, 4.1666668e-2f);
    pc = fmaf(r2, pc, -0.5f);
    float cr = fmaf(r2, pc, 1.0f);
    int n = k & 3;
    float s = (n == 0) ? sr : (n == 1) ? cr : (n == 2) ? -sr : -cr;
    float c = (n == 0) ? cr : (n == 1) ? -sr : (n == 2) ? -cr : sr;
    *sp = s;
    *cp = c;
}

struct Coef {
    float A00m, A11m, A12m, A22i, A12i;   // mass/inertia-folded force rows
    float dv0m, dv1m, dv2i;
    float dc0m, dc1m, dc2i;
    float dxI, dyI;                       // dx*M/I, dy*M/I
    float dx, dy;
};

struct TState { float x, y, th, cth, sth, vxb, vyb, om; };

// One integration step; writes the NEW state row (6 floats) into ob[0..5].
__device__ __forceinline__ void do_step(TState& S, float u0, float u1, float u2,
                                        const Coef& K, float* __restrict__ ob)
{
    const float ex = u0 - S.vxb;
    const float ey = u1 - S.vyb;
    const float ez = u2 - S.om;

    const float Fx = fmaf(K.A00m, ex, -fmaf(K.dv0m, S.vxb, copysignf(K.dc0m, S.vxb)));
    const float Fy = fmaf(K.A11m, ey, fmaf(K.A12m, ez, -fmaf(K.dv1m, S.vyb, copysignf(K.dc1m, S.vyb))));
    const float Tz = fmaf(K.A12i, ey, fmaf(K.A22i, ez, -fmaf(K.dv2i, S.om, copysignf(K.dc2i, S.om))));

    const float al  = fmaf(K.dyI, Fx, fmaf(-K.dxI, Fy, Tz));
    const float om2 = S.om * S.om;

    const float axb = fmaf(-al, K.dy, fmaf(-om2, K.dx, Fx));
    const float ayb = fmaf( al, K.dx, fmaf(-om2, K.dy, Fy));

    const float nom = fmaf(al, DT_F, S.om);
    const float wx  = fmaf(axb, DT_F, S.vxb);   // new velocity, OLD body frame
    const float wy  = fmaf(ayb, DT_F, S.vyb);

    // rotate into new frame: dth = nom*DT (small; damped dynamics)
    const float dth = nom * DT_F;
    const float d2  = dth * dth;
    float sp = fmaf(d2, 8.3333333e-3f, -1.6666667e-1f);
    sp = fmaf(d2, sp, 1.0f);
    const float sd = dth * sp;                       // sin(dth)
    const float cp = fmaf(d2, 4.1666667e-2f, -0.5f);
    const float cd = fmaf(d2, cp, 1.0f);             // cos(dth)

    const float nvxb = fmaf(cd, wx,  sd * wy);       // R(-dth) * w
    const float nvyb = fmaf(cd, wy, -sd * wx);

    // world-frame outputs (OLD c,s: v' = R(th) * w)
    const float nvx = fmaf(S.cth, wx, -(S.sth * wy));
    const float nvy = fmaf(S.sth, wx,  S.cth * wy);

    // advance (c,s); 1 Newton renorm step
    float nc = fmaf(S.cth, cd, -(S.sth * sd));
    float ns = fmaf(S.sth, cd,  S.cth * sd);
    const float rn = fmaf(-0.5f, fmaf(nc, nc, ns * ns), 1.5f);
    nc *= rn;
    ns *= rn;

    const float nx = fmaf(nvx, DT_F, S.x);
    const float ny = fmaf(nvy, DT_F, S.y);
    float nth = S.th + dth;
    nth = fmaf(-rintf(nth * INV_TWO_PI_F), TWO_PI_F, nth);

    S.x = nx; S.y = ny; S.th = nth; S.cth = nc; S.sth = ns;
    S.vxb = nvxb; S.vyb = nvyb; S.om = nom;

    ob[0] = nx;  ob[1] = ny;  ob[2] = nth;
    ob[3] = nvx; ob[4] = nvy; ob[5] = nom;
}

// Batched store of 4 steps (24 floats), start step s0 is odd.
// Row base byte = b*24600 == 8*b (mod 16); step offset 24*s == 8*s (mod 16).
// even b: ptr == 8 (mod 16)  -> f2 + 5*f4 + f2
// odd  b: ptr == 0 (mod 16)  -> 6*f4
__device__ __forceinline__ void store4_even(float* __restrict__ p, const float (&s)[24]) {
    *reinterpret_cast<float2*>(p +  0) = make_float2(s[0], s[1]);
    *reinterpret_cast<float4*>(p +  2) = make_float4(s[2],  s[3],  s[4],  s[5]);
    *reinterpret_cast<float4*>(p +  6) = make_float4(s[6],  s[7],  s[8],  s[9]);
    *reinterpret_cast<float4*>(p + 10) = make_float4(s[10], s[11], s[12], s[13]);
    *reinterpret_cast<float4*>(p + 14) = make_float4(s[14], s[15], s[16], s[17]);
    *reinterpret_cast<float4*>(p + 18) = make_float4(s[18], s[19], s[20], s[21]);
    *reinterpret_cast<float2*>(p + 22) = make_float2(s[22], s[23]);
}
__device__ __forceinline__ void store4_odd(float* __restrict__ p, const float (&s)[24]) {
    *reinterpret_cast<float4*>(p +  0) = make_float4(s[0],  s[1],  s[2],  s[3]);
    *reinterpret_cast<float4*>(p +  4) = make_float4(s[4],  s[5],  s[6],  s[7]);
    *reinterpret_cast<float4*>(p +  8) = make_float4(s[8],  s[9],  s[10], s[11]);
    *reinterpret_cast<float4*>(p + 12) = make_float4(s[12], s[13], s[14], s[15]);
    *reinterpret_cast<float4*>(p + 16) = make_float4(s[16], s[17], s[18], s[19]);
    *reinterpret_cast<float4*>(p + 20) = make_float4(s[20], s[21], s[22], s[23]);
}

__global__ __launch_bounds__(64, 1)
void omni_robot_kernel(const float* __restrict__ init_state,   // (B, 6)
                       const float* __restrict__ cmd_all,      // (B, T, 3)
                       const float* __restrict__ com_offset,   // (2,)
                       const float* __restrict__ inertia_p,    // (1,)
                       const float* __restrict__ gain_p,       // (1,)
                       const float* __restrict__ grip_p,       // (1,)
                       const float* __restrict__ drag_v_p,     // (3,)
                       const float* __restrict__ drag_c_p,     // (3,)
                       float* __restrict__ out,                // (B, T+1, 6)
                       int B, int T)
{
    const int P = (B + 1) >> 1;                 // trajectory pairs
    const int p = blockIdx.x * blockDim.x + threadIdx.x;
    if (p >= P) return;

    const int bA = 2 * p;                       // even row
    const bool hasB = (2 * p + 1) < B;
    const int bB = hasB ? (2 * p + 1) : (B - 1); // odd row (when hasB)

    const float inertia = softplus_f(inertia_p[0]) + 1e-4f;
    const float gain    = softplus_f(gain_p[0]);
    const float grip    = softplus_f(grip_p[0]);
    const float inv_mass    = 1.0f / MASS_F;
    const float inv_inertia = 1.0f / inertia;

    Coef K;
    K.A00m = (gain * M00_F + grip) * inv_mass;
    K.A11m = (gain * M11_F + grip) * inv_mass;
    K.A12m = (gain * M12_F) * inv_mass;
    K.A12i = (gain * M12_F) * inv_inertia;
    K.A22i = (gain * M22_F + grip) * inv_inertia;
    K.dv0m = softplus_f(drag_v_p[0]) * inv_mass;
    K.dv1m = softplus_f(drag_v_p[1]) * inv_mass;
    K.dv2i = softplus_f(drag_v_p[2]) * inv_inertia;
    K.dc0m = softplus_f(drag_c_p[0]) * inv_mass;
    K.dc1m = softplus_f(drag_c_p[1]) * inv_mass;
    K.dc2i = softplus_f(drag_c_p[2]) * inv_inertia;
    K.dx   = com_offset[0];
    K.dy   = com_offset[1];
    K.dxI  = K.dx * MASS_F * inv_inertia;
    K.dyI  = K.dy * MASS_F * inv_inertia;

    TState A, Bs;
    {
        const float* st = init_state + (size_t)bA * 6;
        A.x = st[0]; A.y = st[1]; A.th = st[2];
        float vx = st[3], vy = st[4]; A.om = st[5];
        fast_sincos(A.th, &A.sth, &A.cth);
        A.vxb = fmaf(vx, A.cth, vy * A.sth);
        A.vyb = fmaf(vy, A.cth, -vx * A.sth);
        float* o = out + (size_t)bA * (size_t)(T + 1) * 6;
        ((float2*)o)[0] = make_float2(A.x, A.y);
        ((float2*)o)[1] = make_float2(A.th, vx);
        ((float2*)o)[2] = make_float2(vy, A.om);
    }
    {
        const float* st = init_state + (size_t)bB * 6;
        Bs.x = st[0]; Bs.y = st[1]; Bs.th = st[2];
        float vx = st[3], vy = st[4]; Bs.om = st[5];
        fast_sincos(Bs.th, &Bs.sth, &Bs.cth);
        Bs.vxb = fmaf(vx, Bs.cth, vy * Bs.sth);
        Bs.vyb = fmaf(vy, Bs.cth, -vx * Bs.sth);
        if (hasB) {
            float* o = out + (size_t)bB * (size_t)(T + 1) * 6;
            ((float2*)o)[0] = make_float2(Bs.x, Bs.y);
            ((float2*)o)[1] = make_float2(Bs.th, vx);
            ((float2*)o)[2] = make_float2(vy, Bs.om);
        }
    }

    const float4* __restrict__ c4A = reinterpret_cast<const float4*>(cmd_all + (size_t)bA * T * 3);
    const float4* __restrict__ c4B = reinterpret_cast<const float4*>(cmd_all + (size_t)bB * T * 3);
    const int nch = T / CHUNK;

    // output write cursors: first stored step is s0=1 -> offset 6 floats
    float* __restrict__ pA = out + (size_t)bA * (size_t)(T + 1) * 6 + 6;
    float* __restrict__ pB = out + (size_t)bB * (size_t)(T + 1) * 6 + 6;

    if (nch > 0) {
        float4 curA[6], curB[6], nxtA[6], nxtB[6];
        #pragma unroll
        for (int i = 0; i < 6; ++i) { curA[i] = c4A[i]; curB[i] = c4B[i]; }

        for (int ch = 0; ch < nch; ++ch) {
            // prefetch next chunk (clamped, unconditional)
            {
                const int pf = (ch + 1 < nch) ? (ch + 1) : (nch - 1);
                const float4* sA = c4A + (size_t)pf * 6;
                const float4* sB = c4B + (size_t)pf * 6;
                #pragma unroll
                for (int i = 0; i < 6; ++i) { nxtA[i] = sA[i]; nxtB[i] = sB[i]; }
            }

            float uA[24], uB[24];
            #pragma unroll
            for (int i = 0; i < 6; ++i) {
                uA[4 * i + 0] = curA[i].x; uA[4 * i + 1] = curA[i].y;
                uA[4 * i + 2] = curA[i].z; uA[4 * i + 3] = curA[i].w;
                uB[4 * i + 0] = curB[i].x; uB[4 * i + 1] = curB[i].y;
                uB[4 * i + 2] = curB[i].z; uB[4 * i + 3] = curB[i].w;
            }

            #pragma unroll
            for (int h = 0; h < 2; ++h) {        // two 4-step store batches
                float sA[24], sB[24];
                #pragma unroll
                for (int k = 0; k < 4; ++k) {
                    const int j = 4 * h + k;
                    do_step(A,  uA[3 * j], uA[3 * j + 1], uA[3 * j + 2], K, &sA[6 * k]);
                    do_step(Bs, uB[3 * j], uB[3 * j + 1], uB[3 * j + 2], K, &sB[6 * k]);
                }
                store4_even(pA + 24 * h, sA);
                if (hasB) store4_odd(pB + 24 * h, sB);
            }
            pA += 48;
            pB += 48;

            #pragma unroll
            for (int i = 0; i < 6; ++i) { curA[i] = nxtA[i]; curB[i] = nxtB[i]; }
        }
    }

    // generic tail (T % CHUNK != 0); dead for T=1024.
    if (nch * CHUNK < T) {
        for (int which = 0; which < 2; ++which) {
            if (which == 1 && !hasB) break;
            TState& S = (which == 0) ? A : Bs;
            const int b = (which == 0) ? bA : bB;
            const float* __restrict__ cmd = cmd_all + (size_t)b * T * 3;
            float* __restrict__ o = out + (size_t)b * (size_t)(T + 1) * 6;
            float vx = fmaf(S.cth, S.vxb, -(S.sth * S.vyb));
            float vy = fmaf(S.sth, S.vxb,  S.cth * S.vyb);
            float x = S.x, y = S.y, th = S.th, om = S.om;
            for (int t = nch * CHUNK; t < T; ++t) {
                const float u0 = cmd[3 * t + 0];
                const float u1 = cmd[3 * t + 1];
                const float u2 = cmd[3 * t + 2];
                float c, s;
                fast_sincos(th, &s, &c);
                const float vxb_t = vx * c + vy * s;
                const float vyb_t = vy * c - vx * s;
                const float ex = u0 - vxb_t;
                const float ey = u1 - vyb_t;
                const float ez = u2 - om;
                const float Fx = fmaf(K.A00m, ex, -fmaf(K.dv0m, vxb_t, copysignf(K.dc0m, vxb_t)));
                const float Fy = fmaf(K.A11m, ey, fmaf(K.A12m, ez, -fmaf(K.dv1m, vyb_t, copysignf(K.dc1m, vyb_t))));
                const float Tz = fmaf(K.A12i, ey, fmaf(K.A22i, ez, -fmaf(K.dv2i, om, copysignf(K.dc2i, om))));
                const float al  = fmaf(K.dyI, Fx, fmaf(-K.dxI, Fy, Tz));
                const float om2 = om * om;
                const float axb = fmaf(-al, K.dy, fmaf(-om2, K.dx, Fx));
                const float ayb = fmaf( al, K.dx, fmaf(-om2, K.dy, Fy));
                const float axw = axb * c - ayb * s;
                const float ayw = axb * s + ayb * c;
                vx = vx + axw * DT_F;
                vy = vy + ayw * DT_F;
                om = om + al * DT_F;
                x  = x + vx * DT_F;
                y  = y + vy * DT_F;
                th = th + om * DT_F;
                th = fmaf(-rintf(th * INV_TWO_PI_F), TWO_PI_F, th);
                float* ot = o + (size_t)(t + 1) * 6;
                ((float2*)ot)[0] = make_float2(x, y);
                ((float2*)ot)[1] = make_float2(th, vx);
                ((float2*)ot)[2] = make_float2(vy, om);
            }
        }
    }
}

extern "C" void kernel_launch(void* const* d_in, const int* in_sizes, int n_in,
                              void* d_out, int out_size, void* d_ws, size_t ws_size,
                              hipStream_t stream) {
    const float* init_state = (const float*)d_in[0];
    const float* cmd        = (const float*)d_in[1];
    const float* com_offset = (const float*)d_in[2];
    const float* inertia_p  = (const float*)d_in[3];
    const float* gain_p     = (const float*)d_in[4];
    const float* grip_p     = (const float*)d_in[5];
    const float* drag_v_p   = (const float*)d_in[6];
    const float* drag_c_p   = (const float*)d_in[7];
    float* out = (float*)d_out;

    const int B = in_sizes[0] / 6;
    const int T = in_sizes[1] / (3 * B);

    const int P = (B + 1) / 2;
    const int block = 64;
    const int grid = (P + block - 1) / block;
    hipLaunchKernelGGL(omni_robot_kernel, dim3(grid), dim3(block), 0, stream,
                       init_state, cmd, com_offset, inertia_p, gain_p, grip_p,
                       drag_v_p, drag_c_p, out, B, T);
}

// Round 5
// 386.340 us; speedup vs baseline: 1.3994x; 1.3994x over previous
//
#include <hip/hip_runtime.h>
#include <math.h>

// OmniRobotPhysics: B=8192 independent trajectories, T=1024 sequential steps.
// R6 -> R7: same producer/consumer wave specialization, but the __syncthreads
// is now in UNIFORM control flow (R6 had barriers inside a wave-divergent
// if/else -- formal UB, suspected compile-level hang -> container death).
// Structure: block = 2 waves. Shared for(ch) loop:
//   wave 0: integrate chunk ch (1 traj/lane, register-dbuf cmd prefetch),
//           write states to LDS buf[ch&1] (ds_write_b64 only, NO global
//           stores in the hot loop -> no vmcnt backpressure on compute).
//   wave 1: drain buf[(ch-1)&1] to global with coalesced float2 stores
//           (~2-4 addr groups/instr vs 64-way scatter).
//   one __syncthreads at loop end; epilogue drain for the last chunk.
// Body-frame recurrence + folded constants kept from R3/R5 (numerics identical).

#define MASS_F 2.8f
#define DT_F 0.016f

// F F^T entries (angles {60,130,230,300} deg, R=0.09):
#define M00_F 2.6736481776669306f
#define M11_F 1.3263518223330697f
#define M12_F (-0.025701769743577074f)
#define M22_F 0.0324f

#define TWO_PI_F 6.28318530717958647692f
#define INV_TWO_PI_F 0.15915494309189533577f

#define CHUNK 16
#define OROW 98          // dwords per trajectory row in outbuf (96 data + 2 pad)

__device__ __forceinline__ float softplus_f(float x) {
    float ax = fabsf(x);
    return fmaxf(x, 0.0f) + log1pf(expf(-ax));
}

// Full-range sin/cos: used once per trajectory for th0 (and in the tail).
__device__ __forceinline__ void fast_sincos(float th, float* sp, float* cp) {
    const float INV_PIO2 = 0.63661977236758134f;
    const float PIO2_HI  = 1.57079637050628662109375f;
    const float PIO2_LO  = -4.37113900018624283e-8f;
    float kf = rintf(th * INV_PIO2);
    int   k  = (int)kf;
    float r  = fmaf(-kf, PIO2_HI, th);
    r        = fmaf(-kf, PIO2_LO, r);
    float r2 = r * r;
    float ps = fmaf(r2, 2.7183114e-6f, -1.9515296e-4f);
    ps = fmaf(r2, ps, 8.3333310e-3f);
    ps = fmaf(r2, ps, -1.6666667e-1f);
    float sr = fmaf(r * r2, ps, r);
    float pc = fmaf(r2, 2.4760495e-5f, -1.3888889e-3f);
    pc = fmaf(r2, pc, 4.1666668e-2f);
    pc = fmaf(r2, pc, -0.5f);
    float cr = fmaf(r2, pc, 1.0f);
    int n = k & 3;
    float s = (n == 0) ? sr : (n == 1) ? cr : (n == 2) ? -sr : -cr;
    float c = (n == 0) ? cr : (n == 1) ? -sr : (n == 2) ? -cr : sr;
    *sp = s;
    *cp = c;
}

struct Coef {
    float A00m, A11m, A12m, A22i, A12i;   // mass/inertia-folded force rows
    float dv0m, dv1m, dv2i;
    float dc0m, dc1m, dc2i;
    float dxI, dyI;                       // dx*M/I, dy*M/I
    float dx, dy;
};

struct TState { float x, y, th, cth, sth, vxb, vyb, om; };

// One integration step; writes the NEW state row (6 floats) to LDS at ob.
__device__ __forceinline__ void do_step(TState& S, float u0, float u1, float u2,
                                        const Coef& K, float* __restrict__ ob)
{
    const float ex = u0 - S.vxb;
    const float ey = u1 - S.vyb;
    const float ez = u2 - S.om;

    const float Fx = fmaf(K.A00m, ex, -fmaf(K.dv0m, S.vxb, copysignf(K.dc0m, S.vxb)));
    const float Fy = fmaf(K.A11m, ey, fmaf(K.A12m, ez, -fmaf(K.dv1m, S.vyb, copysignf(K.dc1m, S.vyb))));
    const float Tz = fmaf(K.A12i, ey, fmaf(K.A22i, ez, -fmaf(K.dv2i, S.om, copysignf(K.dc2i, S.om))));

    const float al  = fmaf(K.dyI, Fx, fmaf(-K.dxI, Fy, Tz));
    const float om2 = S.om * S.om;

    const float axb = fmaf(-al, K.dy, fmaf(-om2, K.dx, Fx));
    const float ayb = fmaf( al, K.dx, fmaf(-om2, K.dy, Fy));

    const float nom = fmaf(al, DT_F, S.om);
    const float wx  = fmaf(axb, DT_F, S.vxb);   // new velocity, OLD body frame
    const float wy  = fmaf(ayb, DT_F, S.vyb);

    // rotate into new frame: dth = nom*DT (small; damped dynamics)
    const float dth = nom * DT_F;
    const float d2  = dth * dth;
    float sp = fmaf(d2, 8.3333333e-3f, -1.6666667e-1f);
    sp = fmaf(d2, sp, 1.0f);
    const float sd = dth * sp;                       // sin(dth)
    const float cp = fmaf(d2, 4.1666667e-2f, -0.5f);
    const float cd = fmaf(d2, cp, 1.0f);             // cos(dth)

    const float nvxb = fmaf(cd, wx,  sd * wy);       // R(-dth) * w
    const float nvyb = fmaf(cd, wy, -sd * wx);

    // world-frame outputs (OLD c,s: v' = R(th) * w)
    const float nvx = fmaf(S.cth, wx, -(S.sth * wy));
    const float nvy = fmaf(S.sth, wx,  S.cth * wy);

    // advance (c,s); 1 Newton renorm step
    float nc = fmaf(S.cth, cd, -(S.sth * sd));
    float ns = fmaf(S.sth, cd,  S.cth * sd);
    const float rn = fmaf(-0.5f, fmaf(nc, nc, ns * ns), 1.5f);
    nc *= rn;
    ns *= rn;

    const float nx = fmaf(nvx, DT_F, S.x);
    const float ny = fmaf(nvy, DT_F, S.y);
    float nth = S.th + dth;
    nth = fmaf(-rintf(nth * INV_TWO_PI_F), TWO_PI_F, nth);

    S.x = nx; S.y = ny; S.th = nth; S.cth = nc; S.sth = ns;
    S.vxb = nvxb; S.vyb = nvyb; S.om = nom;

    float2* o2 = reinterpret_cast<float2*>(ob);      // LDS, 8B-aligned
    o2[0] = make_float2(nx, ny);
    o2[1] = make_float2(nth, nvx);
    o2[2] = make_float2(nvy, nom);
}

// IO-wave drain of one chunk: 64 rows x 96 dwords = 3072 float2, coalesced.
// Flat float2 index e = 64*i + lane: row r = e/48, slot cc = e%48.
__device__ __forceinline__ void drain_chunk(const float* __restrict__ src,
                                            int B0, int B, int chd, int lane,
                                            float* __restrict__ out)
{
    const unsigned tb = 96u * (unsigned)chd + 6u;   // dword offset in traj row
    #pragma unroll
    for (int i = 0; i < 48; ++i) {
        const unsigned e  = 64u * i + (unsigned)lane;
        const unsigned m  = e >> 4;
        const unsigned r  = (m * 21846u) >> 16;     // m/3  (m <= 191)
        const unsigned cc = e - 48u * r;            // e % 48
        const float2 v = *reinterpret_cast<const float2*>(&src[r * OROW + 2u * cc]);
        const unsigned g = (unsigned)B0 + r;
        if (g < (unsigned)B) {
            const size_t off = (size_t)g * 6150u + tb + 2u * cc;  // dwords
            *reinterpret_cast<float2*>(out + off) = v;
        }
    }
}

__global__ __launch_bounds__(128, 1)
void omni_robot_kernel(const float* __restrict__ init_state,   // (B, 6)
                       const float* __restrict__ cmd_all,      // (B, T, 3)
                       const float* __restrict__ com_offset,   // (2,)
                       const float* __restrict__ inertia_p,    // (1,)
                       const float* __restrict__ gain_p,       // (1,)
                       const float* __restrict__ grip_p,       // (1,)
                       const float* __restrict__ drag_v_p,     // (3,)
                       const float* __restrict__ drag_c_p,     // (3,)
                       float* __restrict__ out,                // (B, T+1, 6)
                       int B, int T)
{
    __shared__ float outbuf[2][64 * OROW];    // 2 x 24.5 KB

    const int tid  = threadIdx.x;
    const int wid  = tid >> 6;                // 0 = compute wave, 1 = IO wave
    const int lane = tid & 63;
    const int B0   = blockIdx.x * 64;
    const int nch  = T / CHUNK;

    // Per-wave state; only wave 0 initializes/uses the integrator state.
    Coef K;
    TState S;
    float4 cur[12];
    const float4* __restrict__ c4 = nullptr;
    const int b  = B0 + lane;
    const int bc = (b < B) ? b : (B - 1);

    if (wid == 0) {
        const float inertia = softplus_f(inertia_p[0]) + 1e-4f;
        const float gain    = softplus_f(gain_p[0]);
        const float grip    = softplus_f(grip_p[0]);
        const float inv_mass    = 1.0f / MASS_F;
        const float inv_inertia = 1.0f / inertia;

        K.A00m = (gain * M00_F + grip) * inv_mass;
        K.A11m = (gain * M11_F + grip) * inv_mass;
        K.A12m = (gain * M12_F) * inv_mass;
        K.A12i = (gain * M12_F) * inv_inertia;
        K.A22i = (gain * M22_F + grip) * inv_inertia;
        K.dv0m = softplus_f(drag_v_p[0]) * inv_mass;
        K.dv1m = softplus_f(drag_v_p[1]) * inv_mass;
        K.dv2i = softplus_f(drag_v_p[2]) * inv_inertia;
        K.dc0m = softplus_f(drag_c_p[0]) * inv_mass;
        K.dc1m = softplus_f(drag_c_p[1]) * inv_mass;
        K.dc2i = softplus_f(drag_c_p[2]) * inv_inertia;
        K.dx   = com_offset[0];
        K.dy   = com_offset[1];
        K.dxI  = K.dx * MASS_F * inv_inertia;
        K.dyI  = K.dy * MASS_F * inv_inertia;

        const float* st = init_state + (size_t)bc * 6;
        S.x = st[0]; S.y = st[1]; S.th = st[2];
        float vx = st[3], vy = st[4]; S.om = st[5];
        fast_sincos(S.th, &S.sth, &S.cth);
        S.vxb = fmaf(vx, S.cth, vy * S.sth);
        S.vyb = fmaf(vy, S.cth, -vx * S.sth);
        if (b < B) {
            float* o = out + (size_t)b * (size_t)(T + 1) * 6;
            ((float2*)o)[0] = make_float2(S.x, S.y);
            ((float2*)o)[1] = make_float2(S.th, vx);
            ((float2*)o)[2] = make_float2(vy, S.om);
        }

        c4 = reinterpret_cast<const float4*>(cmd_all + (size_t)bc * T * 3);
        if (nch > 0) {
            #pragma unroll
            for (int i = 0; i < 12; ++i) cur[i] = c4[i];
        }
    }

    // ---- shared main loop: barrier in uniform control flow ----
    for (int ch = 0; ch < nch; ++ch) {
        if (wid == 0) {
            // prefetch next chunk (clamped, unconditional)
            float4 nxt[12];
            const int pf = (ch + 1 < nch) ? (ch + 1) : (nch - 1);
            const float4* src = c4 + (size_t)pf * 12;
            #pragma unroll
            for (int i = 0; i < 12; ++i) nxt[i] = src[i];

            float* __restrict__ orow = &outbuf[ch & 1][lane * OROW];
            #pragma unroll
            for (int i = 0; i < 4; ++i) {    // steps 4i..4i+3 (3 float4 each)
                const float4 a  = cur[3 * i + 0];
                const float4 bq = cur[3 * i + 1];
                const float4 cq = cur[3 * i + 2];
                do_step(S, a.x,  a.y,  a.z,  K, orow + 6 * (4 * i + 0));
                do_step(S, a.w,  bq.x, bq.y, K, orow + 6 * (4 * i + 1));
                do_step(S, bq.z, bq.w, cq.x, K, orow + 6 * (4 * i + 2));
                do_step(S, cq.y, cq.z, cq.w, K, orow + 6 * (4 * i + 3));
            }
            #pragma unroll
            for (int i = 0; i < 12; ++i) cur[i] = nxt[i];
        } else if (ch > 0) {
            drain_chunk(&outbuf[(ch - 1) & 1][0], B0, B, ch - 1, lane, out);
        }
        __syncthreads();
    }

    // epilogue: drain the final chunk (written before the last barrier)
    if (wid == 1 && nch > 0) {
        drain_chunk(&outbuf[(nch - 1) & 1][0], B0, B, nch - 1, lane, out);
    }

    // generic tail (T % CHUNK != 0); dead for T=1024.
    if (wid == 0 && nch * CHUNK < T && b < B) {
        const float* __restrict__ cmd = cmd_all + (size_t)b * T * 3;
        float* __restrict__ o = out + (size_t)b * (size_t)(T + 1) * 6;
        float vx = fmaf(S.cth, S.vxb, -(S.sth * S.vyb));
        float vy = fmaf(S.sth, S.vxb,  S.cth * S.vyb);
        float x = S.x, y = S.y, th = S.th, om = S.om;
        for (int t = nch * CHUNK; t < T; ++t) {
            const float u0 = cmd[3 * t + 0];
            const float u1 = cmd[3 * t + 1];
            const float u2 = cmd[3 * t + 2];
            float c, s;
            fast_sincos(th, &s, &c);
            const float vxb_t = vx * c + vy * s;
            const float vyb_t = vy * c - vx * s;
            const float ex = u0 - vxb_t;
            const float ey = u1 - vyb_t;
            const float ez = u2 - om;
            const float Fx = fmaf(K.A00m, ex, -fmaf(K.dv0m, vxb_t, copysignf(K.dc0m, vxb_t)));
            const float Fy = fmaf(K.A11m, ey, fmaf(K.A12m, ez, -fmaf(K.dv1m, vyb_t, copysignf(K.dc1m, vyb_t))));
            const float Tz = fmaf(K.A12i, ey, fmaf(K.A22i, ez, -fmaf(K.dv2i, om, copysignf(K.dc2i, om))));
            const float al  = fmaf(K.dyI, Fx, fmaf(-K.dxI, Fy, Tz));
            const float om2 = om * om;
            const float axb = fmaf(-al, K.dy, fmaf(-om2, K.dx, Fx));
            const float ayb = fmaf( al, K.dx, fmaf(-om2, K.dy, Fy));
            const float axw = axb * c - ayb * s;
            const float ayw = axb * s + ayb * c;
            vx = vx + axw * DT_F;
            vy = vy + ayw * DT_F;
            om = om + al * DT_F;
            x  = x + vx * DT_F;
            y  = y + vy * DT_F;
            th = th + om * DT_F;
            th = fmaf(-rintf(th * INV_TWO_PI_F), TWO_PI_F, th);
            float* ot = o + (size_t)(t + 1) * 6;
            ((float2*)ot)[0] = make_float2(x, y);
            ((float2*)ot)[1] = make_float2(th, vx);
            ((float2*)ot)[2] = make_float2(vy, om);
        }
    }
}

extern "C" void kernel_launch(void* const* d_in, const int* in_sizes, int n_in,
                              void* d_out, int out_size, void* d_ws, size_t ws_size,
                              hipStream_t stream) {
    const float* init_state = (const float*)d_in[0];
    const float* cmd        = (const float*)d_in[1];
    const float* com_offset = (const float*)d_in[2];
    const float* inertia_p  = (const float*)d_in[3];
    const float* gain_p     = (const float*)d_in[4];
    const float* grip_p     = (const float*)d_in[5];
    const float* drag_v_p   = (const float*)d_in[6];
    const float* drag_c_p   = (const float*)d_in[7];
    float* out = (float*)d_out;

    const int B = in_sizes[0] / 6;
    const int T = in_sizes[1] / (3 * B);

    const int block = 128;                    // 2 waves: compute + IO
    const int grid = (B + 63) / 64;
    hipLaunchKernelGGL(omni_robot_kernel, dim3(grid), dim3(block), 0, stream,
                       init_state, cmd, com_offset, inertia_p, gain_p, grip_p,
                       drag_v_p, drag_c_p, out, B, T);
}